// Round 5
// baseline (266.161 us; speedup 1.0000x reference)
//
#include <hip/hip_runtime.h>
#include <hip/hip_bf16.h>

// MHA forward: qkv GEMM (bf16x3 split MFMA) -> flash attention -> proj GEMM.
// B=2, N=2048, C=1024, H=16, D=64.
// R5: GEMM -> 2-phase double-buffer (BK=32, hi/lo interleaved rows, one
//     barrier/iter, prefetch-before-compute) + bijective XCD block swizzle.
//     attn/split unchanged from R4.

typedef unsigned short u16;
typedef __attribute__((ext_vector_type(8))) short bf16x8;
typedef __attribute__((ext_vector_type(4))) float f32x4;

#define DEV static __device__ __forceinline__
#define MFMA(a, b, c) __builtin_amdgcn_mfma_f32_16x16x32_bf16(a, b, c, 0, 0, 0)

DEV u16 f2bf(float f) {
  unsigned u = __float_as_uint(f);
  return (u16)((u + 0x7fffu + ((u >> 16) & 1u)) >> 16);  // RNE
}
DEV float bf2f(u16 h) { return __uint_as_float(((unsigned)h) << 16); }

DEV unsigned pack_bf2(float a, float b) {
  __hip_bfloat162 h2 = __float22bfloat162_rn(make_float2(a, b));
  return *reinterpret_cast<unsigned*>(&h2);
}

DEV void async16(u16* dst, const u16* src) {
  __builtin_amdgcn_global_load_lds(
      (const __attribute__((address_space(1))) unsigned int*)(const void*)src,
      (__attribute__((address_space(3))) unsigned int*)(void*)dst, 16, 0, 0);
}

// ---------------- split fp32 -> bf16 hi/lo (all three inputs, one launch) ----
__global__ __launch_bounds__(256) void k_split_all(
    const float* __restrict__ x, const float* __restrict__ wq,
    const float* __restrict__ wp, u16* __restrict__ xh, u16* __restrict__ xl,
    u16* __restrict__ wqh, u16* __restrict__ wql, u16* __restrict__ wph,
    u16* __restrict__ wpl) {
  int i = blockIdx.x * 256 + threadIdx.x;
  const float* src;
  u16 *dh, *dl;
  int off;
  if (i < 1048576) { src = x;  dh = xh;  dl = xl;  off = i; }
  else if (i < 1835008) { src = wq; dh = wqh; dl = wql; off = i - 1048576; }
  else { src = wp; dh = wph; dl = wpl; off = i - 1835008; }
  float4 v = ((const float4*)src)[off];
  ushort4 h, l;
  h.x = f2bf(v.x); l.x = f2bf(v.x - bf2f(h.x));
  h.y = f2bf(v.y); l.y = f2bf(v.y - bf2f(h.y));
  h.z = f2bf(v.z); l.z = f2bf(v.z - bf2f(h.z));
  h.w = f2bf(v.w); l.w = f2bf(v.w - bf2f(h.w));
  ((ushort4*)dh)[off] = h;
  ((ushort4*)dl)[off] = l;
}

// ---------------- GEMM: C[M][N] = A[M][1024] . B[N][1024]^T + bias ----------------
// 128x128 tile, BK=32, 4 waves (2x2), bf16x3 split (hh + hl + lh).
// 2-phase: prefetch tile kt+1 into buf^1 before computing buf; 1 barrier/iter.
// LDS row layout (per buffer): row = [hi c0..c3 | lo c0..c3], 8 slots x 16B,
// slot involution c = s ^ (row&7) on both stage-source and fragment-read.
template <int MODE>
__global__ __launch_bounds__(256) void k_gemm(
    const u16* __restrict__ Ah_g, const u16* __restrict__ Al_g,
    const u16* __restrict__ Bh_g, const u16* __restrict__ Bl_g,
    const float* __restrict__ bias,
    u16* __restrict__ oQh, u16* __restrict__ oQl,
    u16* __restrict__ oKh, u16* __restrict__ oKl,
    u16* __restrict__ oVh, u16* __restrict__ oVl,
    float* __restrict__ fout, int nbn) {
  // 64KB: 2 buffers x (A[128 rows][64 u16] @0 + B[128 rows][64 u16] @8192)
  __shared__ u16 lds[32768];
  const int t = threadIdx.x;
  const int lane = t & 63, g = lane >> 4, cl = lane & 15;
  const int w = t >> 6;
  // bijective XCD swizzle (gridDim.x % 8 == 0): contiguous mi-rows per XCD
  const int cpx = (nbn * 32) >> 3;
  const int bid = (blockIdx.x & 7) * cpx + (blockIdx.x >> 3);
  const int mi = bid / nbn, ni = bid % nbn;
  const int m0 = mi * 128, n0 = ni * 128;
  const int wr = (w >> 1) * 64, wc = (w & 1) * 64;

  f32x4 acc[4][4] = {};

#define STAGE_AB(kt_, pb_)                                                  \
  {                                                                         \
    const int k0__ = (kt_) * 32;                                            \
    const unsigned pb__ = (pb_);                                            \
    _Pragma("unroll") for (int j = 0; j < 8; ++j) {                         \
      int gs = j * 256 + t;                                                 \
      int tb = gs >> 10;                                                    \
      int s = gs & 1023;                                                    \
      int row = s >> 3;                                                     \
      int c = (s & 7) ^ (row & 7);                                          \
      const u16* hp = tb ? Bh_g : Ah_g;                                     \
      const u16* lp = tb ? Bl_g : Al_g;                                     \
      int r0 = (tb ? n0 : m0) + row;                                        \
      const u16* src = (c < 4) ? hp + r0 * 1024 + k0__ + c * 8              \
                               : lp + r0 * 1024 + k0__ + (c - 4) * 8;       \
      async16(&lds[pb__ + (unsigned)(gs & ~63) * 8], src);                  \
    }                                                                       \
  }

  STAGE_AB(0, 0u);
  __syncthreads();
  unsigned p = 0;

  for (int kt = 0; kt < 32; ++kt) {
    const unsigned base = p * 16384u;
    if (kt < 31) STAGE_AB(kt + 1, base ^ 16384u);

    bf16x8 af[4][2], bfr[4][2];
#pragma unroll
    for (int fm = 0; fm < 4; ++fm) {
      int row = wr + fm * 16 + cl;
      unsigned rb = base + row * 64;
      af[fm][0] = *(const bf16x8*)&lds[rb + ((g ^ (row & 7)) * 8)];
      af[fm][1] = *(const bf16x8*)&lds[rb + (((4 + g) ^ (row & 7)) * 8)];
    }
#pragma unroll
    for (int fn = 0; fn < 4; ++fn) {
      int row = wc + fn * 16 + cl;
      unsigned rb = base + 8192 + row * 64;
      bfr[fn][0] = *(const bf16x8*)&lds[rb + ((g ^ (row & 7)) * 8)];
      bfr[fn][1] = *(const bf16x8*)&lds[rb + (((4 + g) ^ (row & 7)) * 8)];
    }
#pragma unroll
    for (int fm = 0; fm < 4; ++fm)
#pragma unroll
      for (int fn = 0; fn < 4; ++fn) {
        acc[fm][fn] = MFMA(af[fm][0], bfr[fn][0], acc[fm][fn]);
        acc[fm][fn] = MFMA(af[fm][0], bfr[fn][1], acc[fm][fn]);
        acc[fm][fn] = MFMA(af[fm][1], bfr[fn][0], acc[fm][fn]);
      }
    __syncthreads();
    p ^= 1;
  }
#undef STAGE_AB

#pragma unroll
  for (int fm = 0; fm < 4; ++fm) {
#pragma unroll
    for (int fn = 0; fn < 4; ++fn) {
      int cc = n0 + wc + fn * 16 + cl;
      float bv = bias[cc];
      f32x4 a = acc[fm][fn];
#pragma unroll
      for (int r = 0; r < 4; ++r) {
        int rr = m0 + wr + fm * 16 + g * 4 + r;
        float v = a[r] + bv;
        if (MODE == 0) {
          int seg = cc >> 10, cm = cc & 1023;
          int h = cm >> 6, d = cm & 63;
          int b = rr >> 11, n = rr & 2047;
          int bh = b * 16 + h;
          if (seg == 0) {
            v *= 0.1803368801111204f;  // SCALE * log2(e): exp2-domain softmax
            u16 hh = f2bf(v), ll = f2bf(v - bf2f(hh));
            int o = (bh * 2048 + n) * 64 + d;
            oQh[o] = hh; oQl[o] = ll;
          } else if (seg == 1) {
            u16 hh = f2bf(v), ll = f2bf(v - bf2f(hh));
            int o = (bh * 2048 + n) * 64 + d;
            oKh[o] = hh; oKl[o] = ll;
          } else {
            u16 hh = f2bf(v), ll = f2bf(v - bf2f(hh));
            int o = (bh * 64 + d) * 2048 + n;  // V stored transposed [bh][d][n]
            oVh[o] = hh; oVl[o] = ll;
          }
        } else {
          fout[rr * 1024 + cc] = v;
        }
      }
    }
  }
}

// ---------------- flash attention (swapped QK^T, base-2, double-buffered) ----
// grid 512, 4 waves x 32 q-rows = 128 q-rows/block. KV tile = 64 keys.
// LDS: 2 x 32KB K/V double-buffer + 4 x 4KB per-wave P = 80KB -> 2 blocks/CU.
__global__ __launch_bounds__(256) void k_attn(
    const u16* __restrict__ Qh, const u16* __restrict__ Ql,
    const u16* __restrict__ Kh, const u16* __restrict__ Kl,
    const u16* __restrict__ Vh, const u16* __restrict__ Vl,
    u16* __restrict__ Oh, u16* __restrict__ Ol) {
  __shared__ u16 lds[40960];
  const int t = threadIdx.x, w = t >> 6, lane = t & 63, g = lane >> 4, cl = lane & 15;
  int bid = (blockIdx.x & 7) * 64 + (blockIdx.x >> 3);  // same-bh blocks -> same XCD
  const int bh = bid >> 4, qt = bid & 15;
  const int n0 = qt * 128;
  const int PH = 32768 + w * 2048;

  bf16x8 qfh[2][2], qfl[2][2];
#pragma unroll
  for (int fm = 0; fm < 2; ++fm) {
    int rg = bh * 2048 + n0 + w * 32 + fm * 16 + cl;
#pragma unroll
    for (int ks = 0; ks < 2; ++ks) {
      qfh[fm][ks] = *(const bf16x8*)&Qh[rg * 64 + ks * 32 + g * 8];
      qfl[fm][ks] = *(const bf16x8*)&Ql[rg * 64 + ks * 32 + g * 8];
    }
  }

  f32x4 o[2][4] = {};
  float mrun[2] = {-1e30f, -1e30f}, lrun[2] = {0.f, 0.f};
  const int bsrc = (lane & 48) | ((lane >> 2) & 12);  // lane with cl = 4g (same g)

#define STAGE_KV(kt_, pbase_)                                              \
  {                                                                        \
    const int kt__ = (kt_);                                                \
    const unsigned pb__ = (pbase_);                                        \
    _Pragma("unroll") for (int j = 0; j < 8; ++j) {                        \
      int gs = j * 256 + t;                                                \
      int tensor = gs >> 9, s = gs & 511, row = s >> 3;                    \
      int c = (s & 7) ^ (row & 7);                                         \
      const u16* src;                                                      \
      if (tensor == 0)                                                     \
        src = Kh + (bh * 2048 + kt__ * 64 + row) * 64 + c * 8;             \
      else if (tensor == 1)                                                \
        src = Kl + (bh * 2048 + kt__ * 64 + row) * 64 + c * 8;             \
      else if (tensor == 2)                                                \
        src = Vh + (bh * 64 + row) * 2048 + kt__ * 64 + c * 8;             \
      else                                                                 \
        src = Vl + (bh * 64 + row) * 2048 + kt__ * 64 + c * 8;             \
      async16(&lds[pb__ + (unsigned)(gs & ~63) * 8], src);                 \
    }                                                                      \
  }

  STAGE_KV(0, 0u);
  __syncthreads();
  unsigned p = 0;

  for (int kt = 0; kt < 32; ++kt) {
    const unsigned base = p * 16384u;
    if (kt < 31) STAGE_KV(kt + 1, base ^ 16384u);

    f32x4 st[2][4] = {};
    __builtin_amdgcn_s_setprio(1);
#pragma unroll
    for (int fn = 0; fn < 4; ++fn) {
      int krow = fn * 16 + cl;
#pragma unroll
      for (int ks = 0; ks < 2; ++ks) {
        unsigned idx = base + krow * 64 + (((4 * ks + g) ^ (krow & 7)) * 8);
        bf16x8 kfh = *(const bf16x8*)&lds[idx];
        bf16x8 kfl = *(const bf16x8*)&lds[4096 + idx];
#pragma unroll
        for (int fm = 0; fm < 2; ++fm) {
          st[fm][fn] = MFMA(kfh, qfh[fm][ks], st[fm][fn]);
          st[fm][fn] = MFMA(kfl, qfh[fm][ks], st[fm][fn]);
          st[fm][fn] = MFMA(kfh, qfl[fm][ks], st[fm][fn]);
        }
      }
    }
    __builtin_amdgcn_s_setprio(0);

#pragma unroll
    for (int fm = 0; fm < 2; ++fm) {
      float pmax;
      {
        float a = fmaxf(fmaxf(st[fm][0][0], st[fm][0][1]),
                        fmaxf(st[fm][0][2], st[fm][0][3]));
        float b = fmaxf(fmaxf(st[fm][1][0], st[fm][1][1]),
                        fmaxf(st[fm][1][2], st[fm][1][3]));
        float c = fmaxf(fmaxf(st[fm][2][0], st[fm][2][1]),
                        fmaxf(st[fm][2][2], st[fm][2][3]));
        float d = fmaxf(fmaxf(st[fm][3][0], st[fm][3][1]),
                        fmaxf(st[fm][3][2], st[fm][3][3]));
        pmax = fmaxf(fmaxf(a, b), fmaxf(c, d));
      }
      pmax = fmaxf(pmax, __shfl_xor(pmax, 16));
      pmax = fmaxf(pmax, __shfl_xor(pmax, 32));
      if (__any(pmax > mrun[fm] + 8.0f)) {
        float mnew = fmaxf(mrun[fm], pmax);
        float esc = __builtin_amdgcn_exp2f(mrun[fm] - mnew);
        mrun[fm] = mnew;
        lrun[fm] *= esc;
        float e0 = __shfl(esc, bsrc), e1 = __shfl(esc, bsrc | 1);
        float e2 = __shfl(esc, bsrc | 2), e3 = __shfl(esc, bsrc | 3);
#pragma unroll
        for (int fd = 0; fd < 4; ++fd) {
          o[fm][fd][0] *= e0; o[fm][fd][1] *= e1;
          o[fm][fd][2] *= e2; o[fm][fd][3] *= e3;
        }
      }
      float psum = 0.f;
      unsigned upk[4][2];
#pragma unroll
      for (int fn = 0; fn < 4; ++fn) {
        float p0 = __builtin_amdgcn_exp2f(st[fm][fn][0] - mrun[fm]);
        float p1 = __builtin_amdgcn_exp2f(st[fm][fn][1] - mrun[fm]);
        float p2 = __builtin_amdgcn_exp2f(st[fm][fn][2] - mrun[fm]);
        float p3 = __builtin_amdgcn_exp2f(st[fm][fn][3] - mrun[fm]);
        psum += (p0 + p1) + (p2 + p3);
        upk[fn][0] = pack_bf2(p0, p1);
        upk[fn][1] = pack_bf2(p2, p3);
      }
      psum += __shfl_xor(psum, 16);
      psum += __shfl_xor(psum, 32);
      lrun[fm] += psum;
      int rq = fm * 16 + cl;
      int swz = (rq & 7) << 3;
#pragma unroll
      for (int fn = 0; fn < 4; ++fn) {
        int addr = (rq * 64 + fn * 16 + 4 * g) ^ swz;
        *(uint2*)&lds[PH + addr] = make_uint2(upk[fn][0], upk[fn][1]);
      }
    }

    bf16x8 pa[2][2];
#pragma unroll
    for (int fm = 0; fm < 2; ++fm) {
      int rq = fm * 16 + cl;
      int swz = (rq & 7) << 3;
#pragma unroll
      for (int ks = 0; ks < 2; ++ks) {
        int addr = (rq * 64 + ks * 32 + 8 * g) ^ swz;
        pa[fm][ks] = *(const bf16x8*)&lds[PH + addr];
      }
    }

    __builtin_amdgcn_s_setprio(1);
#pragma unroll
    for (int fd = 0; fd < 4; ++fd) {
      int vrow = fd * 16 + cl;
#pragma unroll
      for (int ks = 0; ks < 2; ++ks) {
        unsigned idx = base + 8192 + vrow * 64 + (((4 * ks + g) ^ (vrow & 7)) * 8);
        bf16x8 vfh = *(const bf16x8*)&lds[idx];
        bf16x8 vfl = *(const bf16x8*)&lds[4096 + idx];
#pragma unroll
        for (int fm = 0; fm < 2; ++fm) {
          o[fm][fd] = MFMA(pa[fm][ks], vfh, o[fm][fd]);
          o[fm][fd] = MFMA(pa[fm][ks], vfl, o[fm][fd]);
        }
      }
    }
    __builtin_amdgcn_s_setprio(0);
    __syncthreads();
    p ^= 1;
  }
#undef STAGE_KV

  const int b = bh >> 4, h = bh & 15;
#pragma unroll
  for (int fm = 0; fm < 2; ++fm) {
    float l0 = __shfl(lrun[fm], bsrc), l1 = __shfl(lrun[fm], bsrc | 1);
    float l2 = __shfl(lrun[fm], bsrc | 2), l3 = __shfl(lrun[fm], bsrc | 3);
    float inv[4] = {1.0f / l0, 1.0f / l1, 1.0f / l2, 1.0f / l3};
#pragma unroll
    for (int fd = 0; fd < 4; ++fd)
#pragma unroll
      for (int r = 0; r < 4; ++r) {
        float v = o[fm][fd][r] * inv[r];
        u16 hh = f2bf(v), ll = f2bf(v - bf2f(hh));
        int rowg = b * 2048 + n0 + w * 32 + fm * 16 + 4 * g + r;
        int colg = h * 64 + fd * 16 + cl;
        Oh[rowg * 1024 + colg] = hh;
        Ol[rowg * 1024 + colg] = ll;
      }
  }
}

extern "C" void kernel_launch(void* const* d_in, const int* in_sizes, int n_in,
                              void* d_out, int out_size, void* d_ws, size_t ws_size,
                              hipStream_t stream) {
  const float* x  = (const float*)d_in[0];
  const float* Wq = (const float*)d_in[1];
  const float* bq = (const float*)d_in[2];
  const float* Wp = (const float*)d_in[3];
  const float* bp = (const float*)d_in[4];
  float* out = (float*)d_out;
  char* ws = (char*)d_ws;

  u16* Xh  = (u16*)(ws + 0);         // also Oh
  u16* Xl  = (u16*)(ws + 8388608);   // also Ol
  u16* Wqh = (u16*)(ws + 16777216);
  u16* Wql = (u16*)(ws + 23068672);
  u16* Wph = (u16*)(ws + 29360128);
  u16* Wpl = (u16*)(ws + 31457280);
  u16* Qh  = (u16*)(ws + 33554432);
  u16* Ql  = (u16*)(ws + 41943040);
  u16* Kh  = (u16*)(ws + 50331648);
  u16* Kl  = (u16*)(ws + 58720256);
  u16* Vh  = (u16*)(ws + 67108864);
  u16* Vl  = (u16*)(ws + 75497472);  // end 83886080 (80MB)

  k_split_all<<<8192, 256, 0, stream>>>(x, Wq, Wp, Xh, Xl, Wqh, Wql, Wph, Wpl);

  k_gemm<0><<<32 * 24, 256, 0, stream>>>(Xh, Xl, Wqh, Wql, bq,
                                         Qh, Ql, Kh, Kl, Vh, Vl, nullptr, 24);
  k_attn<<<512, 256, 0, stream>>>(Qh, Ql, Kh, Kl, Vh, Vl, Xh, Xl);
  k_gemm<1><<<32 * 8, 256, 0, stream>>>(Xh, Xl, Wph, Wpl, bp,
                                        nullptr, nullptr, nullptr, nullptr,
                                        nullptr, nullptr, out, 8);
}

// Round 6
// 257.131 us; speedup vs baseline: 1.0351x; 1.0351x over previous
//
#include <hip/hip_runtime.h>
#include <hip/hip_bf16.h>

// MHA forward: qkv GEMM (bf16x3 split MFMA) -> flash attention -> proj GEMM.
// B=2, N=2048, C=1024, H=16, D=64.
// R6: GEMM back to R4's serial-stage BK=64 structure, but 512 threads/block
//     (8 waves, 2x4 wave grid, 64x32 per wave) for 2x TLP. No XCD swizzle.
//     attn (R4 double-buffered) and split unchanged.

typedef unsigned short u16;
typedef __attribute__((ext_vector_type(8))) short bf16x8;
typedef __attribute__((ext_vector_type(4))) float f32x4;

#define DEV static __device__ __forceinline__
#define MFMA(a, b, c) __builtin_amdgcn_mfma_f32_16x16x32_bf16(a, b, c, 0, 0, 0)

DEV u16 f2bf(float f) {
  unsigned u = __float_as_uint(f);
  return (u16)((u + 0x7fffu + ((u >> 16) & 1u)) >> 16);  // RNE
}
DEV float bf2f(u16 h) { return __uint_as_float(((unsigned)h) << 16); }

DEV unsigned pack_bf2(float a, float b) {
  __hip_bfloat162 h2 = __float22bfloat162_rn(make_float2(a, b));
  return *reinterpret_cast<unsigned*>(&h2);
}

DEV void async16(u16* dst, const u16* src) {
  __builtin_amdgcn_global_load_lds(
      (const __attribute__((address_space(1))) unsigned int*)(const void*)src,
      (__attribute__((address_space(3))) unsigned int*)(void*)dst, 16, 0, 0);
}

// ---------------- split fp32 -> bf16 hi/lo (all three inputs, one launch) ----
__global__ __launch_bounds__(256) void k_split_all(
    const float* __restrict__ x, const float* __restrict__ wq,
    const float* __restrict__ wp, u16* __restrict__ xh, u16* __restrict__ xl,
    u16* __restrict__ wqh, u16* __restrict__ wql, u16* __restrict__ wph,
    u16* __restrict__ wpl) {
  int i = blockIdx.x * 256 + threadIdx.x;
  const float* src;
  u16 *dh, *dl;
  int off;
  if (i < 1048576) { src = x;  dh = xh;  dl = xl;  off = i; }
  else if (i < 1835008) { src = wq; dh = wqh; dl = wql; off = i - 1048576; }
  else { src = wp; dh = wph; dl = wpl; off = i - 1835008; }
  float4 v = ((const float4*)src)[off];
  ushort4 h, l;
  h.x = f2bf(v.x); l.x = f2bf(v.x - bf2f(h.x));
  h.y = f2bf(v.y); l.y = f2bf(v.y - bf2f(h.y));
  h.z = f2bf(v.z); l.z = f2bf(v.z - bf2f(h.z));
  h.w = f2bf(v.w); l.w = f2bf(v.w - bf2f(h.w));
  ((ushort4*)dh)[off] = h;
  ((ushort4*)dl)[off] = l;
}

// ---------------- GEMM: C[M][N] = A[M][1024] . B[N][1024]^T + bias ----------------
// 128x128 tile, BK=64, 8 waves (2x4 grid, 64x32 per wave), bf16x3 split.
// Serial stage -> barrier -> compute -> barrier (R4 structure), 16 K-iters.
template <int MODE>
__global__ __launch_bounds__(512) void k_gemm(
    const u16* __restrict__ Ah_g, const u16* __restrict__ Al_g,
    const u16* __restrict__ Bh_g, const u16* __restrict__ Bl_g,
    const float* __restrict__ bias,
    u16* __restrict__ oQh, u16* __restrict__ oQl,
    u16* __restrict__ oKh, u16* __restrict__ oKl,
    u16* __restrict__ oVh, u16* __restrict__ oVl,
    float* __restrict__ fout, int nbn) {
  // LDS 64KB: Ah[128][64] @0, Al @8192, Bh @16384, Bl @24576 (u16 units).
  __shared__ u16 lds[32768];
  const int t = threadIdx.x;
  const int lane = t & 63, g = lane >> 4, cl = lane & 15;
  const int w = t >> 6;
  const int mi = blockIdx.x / nbn, ni = blockIdx.x % nbn;
  const int m0 = mi * 128, n0 = ni * 128;
  const int wr = (w >> 2) * 64, wc = (w & 3) * 32;

  f32x4 acc[4][2] = {};

  for (int kt = 0; kt < 16; ++kt) {
    const int k0 = kt * 64;
    // stage 4 tensors x 1024 chunks of 16B; linear LDS dest, swizzled source
#pragma unroll
    for (int j = 0; j < 8; ++j) {
      int gs = j * 512 + t;
      int tensor = gs >> 10;
      int s = gs & 1023;
      int row = s >> 3;
      int c = (s & 7) ^ (row & 7);
      const u16* src;
      if (tensor == 0)      src = Ah_g + (m0 + row) * 1024 + k0 + c * 8;
      else if (tensor == 1) src = Al_g + (m0 + row) * 1024 + k0 + c * 8;
      else if (tensor == 2) src = Bh_g + (n0 + row) * 1024 + k0 + c * 8;
      else                  src = Bl_g + (n0 + row) * 1024 + k0 + c * 8;
      async16(&lds[(unsigned)(gs & ~63) * 8], src);
    }
    __syncthreads();

#pragma unroll
    for (int ks = 0; ks < 2; ++ks) {
      bf16x8 af[4][2], bfr[2][2];
#pragma unroll
      for (int fm = 0; fm < 4; ++fm) {
        int rowL = wr + fm * 16 + cl;
        int idx = rowL * 64 + (((4 * ks + g) ^ (rowL & 7)) * 8);
        af[fm][0] = *(const bf16x8*)&lds[idx];
        af[fm][1] = *(const bf16x8*)&lds[8192 + idx];
      }
#pragma unroll
      for (int fn = 0; fn < 2; ++fn) {
        int rowL = wc + fn * 16 + cl;
        int idx = rowL * 64 + (((4 * ks + g) ^ (rowL & 7)) * 8);
        bfr[fn][0] = *(const bf16x8*)&lds[16384 + idx];
        bfr[fn][1] = *(const bf16x8*)&lds[24576 + idx];
      }
#pragma unroll
      for (int fm = 0; fm < 4; ++fm)
#pragma unroll
        for (int fn = 0; fn < 2; ++fn) {
          acc[fm][fn] = MFMA(af[fm][0], bfr[fn][0], acc[fm][fn]);
          acc[fm][fn] = MFMA(af[fm][0], bfr[fn][1], acc[fm][fn]);
          acc[fm][fn] = MFMA(af[fm][1], bfr[fn][0], acc[fm][fn]);
        }
    }
    __syncthreads();
  }

  // epilogue
#pragma unroll
  for (int fm = 0; fm < 4; ++fm) {
#pragma unroll
    for (int fn = 0; fn < 2; ++fn) {
      int cc = n0 + wc + fn * 16 + cl;
      float bv = bias[cc];
      f32x4 a = acc[fm][fn];
#pragma unroll
      for (int r = 0; r < 4; ++r) {
        int rr = m0 + wr + fm * 16 + g * 4 + r;
        float v = a[r] + bv;
        if (MODE == 0) {
          int seg = cc >> 10, cm = cc & 1023;
          int h = cm >> 6, d = cm & 63;
          int b = rr >> 11, n = rr & 2047;
          int bh = b * 16 + h;
          if (seg == 0) {
            v *= 0.1803368801111204f;  // SCALE * log2(e): exp2-domain softmax
            u16 hh = f2bf(v), ll = f2bf(v - bf2f(hh));
            int o = (bh * 2048 + n) * 64 + d;
            oQh[o] = hh; oQl[o] = ll;
          } else if (seg == 1) {
            u16 hh = f2bf(v), ll = f2bf(v - bf2f(hh));
            int o = (bh * 2048 + n) * 64 + d;
            oKh[o] = hh; oKl[o] = ll;
          } else {
            u16 hh = f2bf(v), ll = f2bf(v - bf2f(hh));
            int o = (bh * 64 + d) * 2048 + n;  // V stored transposed [bh][d][n]
            oVh[o] = hh; oVl[o] = ll;
          }
        } else {
          fout[rr * 1024 + cc] = v;
        }
      }
    }
  }
}

// ---------------- flash attention (swapped QK^T, base-2, double-buffered) ----
// grid 512, 4 waves x 32 q-rows = 128 q-rows/block. KV tile = 64 keys.
// LDS: 2 x 32KB K/V double-buffer + 4 x 4KB per-wave P = 80KB -> 2 blocks/CU.
__global__ __launch_bounds__(256) void k_attn(
    const u16* __restrict__ Qh, const u16* __restrict__ Ql,
    const u16* __restrict__ Kh, const u16* __restrict__ Kl,
    const u16* __restrict__ Vh, const u16* __restrict__ Vl,
    u16* __restrict__ Oh, u16* __restrict__ Ol) {
  __shared__ u16 lds[40960];
  const int t = threadIdx.x, w = t >> 6, lane = t & 63, g = lane >> 4, cl = lane & 15;
  int bid = (blockIdx.x & 7) * 64 + (blockIdx.x >> 3);  // same-bh blocks -> same XCD
  const int bh = bid >> 4, qt = bid & 15;
  const int n0 = qt * 128;
  const int PH = 32768 + w * 2048;

  bf16x8 qfh[2][2], qfl[2][2];
#pragma unroll
  for (int fm = 0; fm < 2; ++fm) {
    int rg = bh * 2048 + n0 + w * 32 + fm * 16 + cl;
#pragma unroll
    for (int ks = 0; ks < 2; ++ks) {
      qfh[fm][ks] = *(const bf16x8*)&Qh[rg * 64 + ks * 32 + g * 8];
      qfl[fm][ks] = *(const bf16x8*)&Ql[rg * 64 + ks * 32 + g * 8];
    }
  }

  f32x4 o[2][4] = {};
  float mrun[2] = {-1e30f, -1e30f}, lrun[2] = {0.f, 0.f};
  const int bsrc = (lane & 48) | ((lane >> 2) & 12);  // lane with cl = 4g (same g)

#define STAGE_KV(kt_, pbase_)                                              \
  {                                                                        \
    const int kt__ = (kt_);                                                \
    const unsigned pb__ = (pbase_);                                        \
    _Pragma("unroll") for (int j = 0; j < 8; ++j) {                        \
      int gs = j * 256 + t;                                                \
      int tensor = gs >> 9, s = gs & 511, row = s >> 3;                    \
      int c = (s & 7) ^ (row & 7);                                         \
      const u16* src;                                                      \
      if (tensor == 0)                                                     \
        src = Kh + (bh * 2048 + kt__ * 64 + row) * 64 + c * 8;             \
      else if (tensor == 1)                                                \
        src = Kl + (bh * 2048 + kt__ * 64 + row) * 64 + c * 8;             \
      else if (tensor == 2)                                                \
        src = Vh + (bh * 64 + row) * 2048 + kt__ * 64 + c * 8;             \
      else                                                                 \
        src = Vl + (bh * 64 + row) * 2048 + kt__ * 64 + c * 8;             \
      async16(&lds[pb__ + (unsigned)(gs & ~63) * 8], src);                 \
    }                                                                      \
  }

  STAGE_KV(0, 0u);
  __syncthreads();
  unsigned p = 0;

  for (int kt = 0; kt < 32; ++kt) {
    const unsigned base = p * 16384u;
    if (kt < 31) STAGE_KV(kt + 1, base ^ 16384u);

    f32x4 st[2][4] = {};
    __builtin_amdgcn_s_setprio(1);
#pragma unroll
    for (int fn = 0; fn < 4; ++fn) {
      int krow = fn * 16 + cl;
#pragma unroll
      for (int ks = 0; ks < 2; ++ks) {
        unsigned idx = base + krow * 64 + (((4 * ks + g) ^ (krow & 7)) * 8);
        bf16x8 kfh = *(const bf16x8*)&lds[idx];
        bf16x8 kfl = *(const bf16x8*)&lds[4096 + idx];
#pragma unroll
        for (int fm = 0; fm < 2; ++fm) {
          st[fm][fn] = MFMA(kfh, qfh[fm][ks], st[fm][fn]);
          st[fm][fn] = MFMA(kfl, qfh[fm][ks], st[fm][fn]);
          st[fm][fn] = MFMA(kfh, qfl[fm][ks], st[fm][fn]);
        }
      }
    }
    __builtin_amdgcn_s_setprio(0);

#pragma unroll
    for (int fm = 0; fm < 2; ++fm) {
      float pmax;
      {
        float a = fmaxf(fmaxf(st[fm][0][0], st[fm][0][1]),
                        fmaxf(st[fm][0][2], st[fm][0][3]));
        float b = fmaxf(fmaxf(st[fm][1][0], st[fm][1][1]),
                        fmaxf(st[fm][1][2], st[fm][1][3]));
        float c = fmaxf(fmaxf(st[fm][2][0], st[fm][2][1]),
                        fmaxf(st[fm][2][2], st[fm][2][3]));
        float d = fmaxf(fmaxf(st[fm][3][0], st[fm][3][1]),
                        fmaxf(st[fm][3][2], st[fm][3][3]));
        pmax = fmaxf(fmaxf(a, b), fmaxf(c, d));
      }
      pmax = fmaxf(pmax, __shfl_xor(pmax, 16));
      pmax = fmaxf(pmax, __shfl_xor(pmax, 32));
      if (__any(pmax > mrun[fm] + 8.0f)) {
        float mnew = fmaxf(mrun[fm], pmax);
        float esc = __builtin_amdgcn_exp2f(mrun[fm] - mnew);
        mrun[fm] = mnew;
        lrun[fm] *= esc;
        float e0 = __shfl(esc, bsrc), e1 = __shfl(esc, bsrc | 1);
        float e2 = __shfl(esc, bsrc | 2), e3 = __shfl(esc, bsrc | 3);
#pragma unroll
        for (int fd = 0; fd < 4; ++fd) {
          o[fm][fd][0] *= e0; o[fm][fd][1] *= e1;
          o[fm][fd][2] *= e2; o[fm][fd][3] *= e3;
        }
      }
      float psum = 0.f;
      unsigned upk[4][2];
#pragma unroll
      for (int fn = 0; fn < 4; ++fn) {
        float p0 = __builtin_amdgcn_exp2f(st[fm][fn][0] - mrun[fm]);
        float p1 = __builtin_amdgcn_exp2f(st[fm][fn][1] - mrun[fm]);
        float p2 = __builtin_amdgcn_exp2f(st[fm][fn][2] - mrun[fm]);
        float p3 = __builtin_amdgcn_exp2f(st[fm][fn][3] - mrun[fm]);
        psum += (p0 + p1) + (p2 + p3);
        upk[fn][0] = pack_bf2(p0, p1);
        upk[fn][1] = pack_bf2(p2, p3);
      }
      psum += __shfl_xor(psum, 16);
      psum += __shfl_xor(psum, 32);
      lrun[fm] += psum;
      int rq = fm * 16 + cl;
      int swz = (rq & 7) << 3;
#pragma unroll
      for (int fn = 0; fn < 4; ++fn) {
        int addr = (rq * 64 + fn * 16 + 4 * g) ^ swz;
        *(uint2*)&lds[PH + addr] = make_uint2(upk[fn][0], upk[fn][1]);
      }
    }

    bf16x8 pa[2][2];
#pragma unroll
    for (int fm = 0; fm < 2; ++fm) {
      int rq = fm * 16 + cl;
      int swz = (rq & 7) << 3;
#pragma unroll
      for (int ks = 0; ks < 2; ++ks) {
        int addr = (rq * 64 + ks * 32 + 8 * g) ^ swz;
        pa[fm][ks] = *(const bf16x8*)&lds[PH + addr];
      }
    }

    __builtin_amdgcn_s_setprio(1);
#pragma unroll
    for (int fd = 0; fd < 4; ++fd) {
      int vrow = fd * 16 + cl;
#pragma unroll
      for (int ks = 0; ks < 2; ++ks) {
        unsigned idx = base + 8192 + vrow * 64 + (((4 * ks + g) ^ (vrow & 7)) * 8);
        bf16x8 vfh = *(const bf16x8*)&lds[idx];
        bf16x8 vfl = *(const bf16x8*)&lds[4096 + idx];
#pragma unroll
        for (int fm = 0; fm < 2; ++fm) {
          o[fm][fd] = MFMA(pa[fm][ks], vfh, o[fm][fd]);
          o[fm][fd] = MFMA(pa[fm][ks], vfl, o[fm][fd]);
        }
      }
    }
    __builtin_amdgcn_s_setprio(0);
    __syncthreads();
    p ^= 1;
  }
#undef STAGE_KV

  const int b = bh >> 4, h = bh & 15;
#pragma unroll
  for (int fm = 0; fm < 2; ++fm) {
    float l0 = __shfl(lrun[fm], bsrc), l1 = __shfl(lrun[fm], bsrc | 1);
    float l2 = __shfl(lrun[fm], bsrc | 2), l3 = __shfl(lrun[fm], bsrc | 3);
    float inv[4] = {1.0f / l0, 1.0f / l1, 1.0f / l2, 1.0f / l3};
#pragma unroll
    for (int fd = 0; fd < 4; ++fd)
#pragma unroll
      for (int r = 0; r < 4; ++r) {
        float v = o[fm][fd][r] * inv[r];
        u16 hh = f2bf(v), ll = f2bf(v - bf2f(hh));
        int rowg = b * 2048 + n0 + w * 32 + fm * 16 + 4 * g + r;
        int colg = h * 64 + fd * 16 + cl;
        Oh[rowg * 1024 + colg] = hh;
        Ol[rowg * 1024 + colg] = ll;
      }
  }
}

extern "C" void kernel_launch(void* const* d_in, const int* in_sizes, int n_in,
                              void* d_out, int out_size, void* d_ws, size_t ws_size,
                              hipStream_t stream) {
  const float* x  = (const float*)d_in[0];
  const float* Wq = (const float*)d_in[1];
  const float* bq = (const float*)d_in[2];
  const float* Wp = (const float*)d_in[3];
  const float* bp = (const float*)d_in[4];
  float* out = (float*)d_out;
  char* ws = (char*)d_ws;

  u16* Xh  = (u16*)(ws + 0);         // also Oh
  u16* Xl  = (u16*)(ws + 8388608);   // also Ol
  u16* Wqh = (u16*)(ws + 16777216);
  u16* Wql = (u16*)(ws + 23068672);
  u16* Wph = (u16*)(ws + 29360128);
  u16* Wpl = (u16*)(ws + 31457280);
  u16* Qh  = (u16*)(ws + 33554432);
  u16* Ql  = (u16*)(ws + 41943040);
  u16* Kh  = (u16*)(ws + 50331648);
  u16* Kl  = (u16*)(ws + 58720256);
  u16* Vh  = (u16*)(ws + 67108864);
  u16* Vl  = (u16*)(ws + 75497472);  // end 83886080 (80MB)

  k_split_all<<<8192, 256, 0, stream>>>(x, Wq, Wp, Xh, Xl, Wqh, Wql, Wph, Wpl);

  k_gemm<0><<<32 * 24, 512, 0, stream>>>(Xh, Xl, Wqh, Wql, bq,
                                         Qh, Ql, Kh, Kl, Vh, Vl, nullptr, 24);
  k_attn<<<512, 256, 0, stream>>>(Qh, Ql, Kh, Kl, Vh, Vl, Xh, Xl);
  k_gemm<1><<<32 * 8, 512, 0, stream>>>(Xh, Xl, Wph, Wpl, bp,
                                        nullptr, nullptr, nullptr, nullptr,
                                        nullptr, nullptr, out, 8);
}

// Round 7
// 246.224 us; speedup vs baseline: 1.0810x; 1.0443x over previous
//
#include <hip/hip_runtime.h>
#include <hip/hip_bf16.h>

// MHA forward: qkv GEMM (bf16x3 split MFMA) -> flash attention -> proj GEMM.
// B=2, N=2048, C=1024, H=16, D=64.
// R7: attn -> 8 waves x 16 q-rows (128 rows/block unchanged, 80KB LDS
//     unchanged -> 2 blocks/CU x 512 thr = 16 waves/CU, 2x TLP).
//     GEMM (R6 8-wave) and split unchanged.

typedef unsigned short u16;
typedef __attribute__((ext_vector_type(8))) short bf16x8;
typedef __attribute__((ext_vector_type(4))) float f32x4;

#define DEV static __device__ __forceinline__
#define MFMA(a, b, c) __builtin_amdgcn_mfma_f32_16x16x32_bf16(a, b, c, 0, 0, 0)

DEV u16 f2bf(float f) {
  unsigned u = __float_as_uint(f);
  return (u16)((u + 0x7fffu + ((u >> 16) & 1u)) >> 16);  // RNE
}
DEV float bf2f(u16 h) { return __uint_as_float(((unsigned)h) << 16); }

DEV unsigned pack_bf2(float a, float b) {
  __hip_bfloat162 h2 = __float22bfloat162_rn(make_float2(a, b));
  return *reinterpret_cast<unsigned*>(&h2);
}

DEV void async16(u16* dst, const u16* src) {
  __builtin_amdgcn_global_load_lds(
      (const __attribute__((address_space(1))) unsigned int*)(const void*)src,
      (__attribute__((address_space(3))) unsigned int*)(void*)dst, 16, 0, 0);
}

// ---------------- split fp32 -> bf16 hi/lo (all three inputs, one launch) ----
__global__ __launch_bounds__(256) void k_split_all(
    const float* __restrict__ x, const float* __restrict__ wq,
    const float* __restrict__ wp, u16* __restrict__ xh, u16* __restrict__ xl,
    u16* __restrict__ wqh, u16* __restrict__ wql, u16* __restrict__ wph,
    u16* __restrict__ wpl) {
  int i = blockIdx.x * 256 + threadIdx.x;
  const float* src;
  u16 *dh, *dl;
  int off;
  if (i < 1048576) { src = x;  dh = xh;  dl = xl;  off = i; }
  else if (i < 1835008) { src = wq; dh = wqh; dl = wql; off = i - 1048576; }
  else { src = wp; dh = wph; dl = wpl; off = i - 1835008; }
  float4 v = ((const float4*)src)[off];
  ushort4 h, l;
  h.x = f2bf(v.x); l.x = f2bf(v.x - bf2f(h.x));
  h.y = f2bf(v.y); l.y = f2bf(v.y - bf2f(h.y));
  h.z = f2bf(v.z); l.z = f2bf(v.z - bf2f(h.z));
  h.w = f2bf(v.w); l.w = f2bf(v.w - bf2f(h.w));
  ((ushort4*)dh)[off] = h;
  ((ushort4*)dl)[off] = l;
}

// ---------------- GEMM: C[M][N] = A[M][1024] . B[N][1024]^T + bias ----------------
// 128x128 tile, BK=64, 8 waves (2x4 grid, 64x32 per wave), bf16x3 split.
template <int MODE>
__global__ __launch_bounds__(512) void k_gemm(
    const u16* __restrict__ Ah_g, const u16* __restrict__ Al_g,
    const u16* __restrict__ Bh_g, const u16* __restrict__ Bl_g,
    const float* __restrict__ bias,
    u16* __restrict__ oQh, u16* __restrict__ oQl,
    u16* __restrict__ oKh, u16* __restrict__ oKl,
    u16* __restrict__ oVh, u16* __restrict__ oVl,
    float* __restrict__ fout, int nbn) {
  __shared__ u16 lds[32768];
  const int t = threadIdx.x;
  const int lane = t & 63, g = lane >> 4, cl = lane & 15;
  const int w = t >> 6;
  const int mi = blockIdx.x / nbn, ni = blockIdx.x % nbn;
  const int m0 = mi * 128, n0 = ni * 128;
  const int wr = (w >> 2) * 64, wc = (w & 3) * 32;

  f32x4 acc[4][2] = {};

  for (int kt = 0; kt < 16; ++kt) {
    const int k0 = kt * 64;
#pragma unroll
    for (int j = 0; j < 8; ++j) {
      int gs = j * 512 + t;
      int tensor = gs >> 10;
      int s = gs & 1023;
      int row = s >> 3;
      int c = (s & 7) ^ (row & 7);
      const u16* src;
      if (tensor == 0)      src = Ah_g + (m0 + row) * 1024 + k0 + c * 8;
      else if (tensor == 1) src = Al_g + (m0 + row) * 1024 + k0 + c * 8;
      else if (tensor == 2) src = Bh_g + (n0 + row) * 1024 + k0 + c * 8;
      else                  src = Bl_g + (n0 + row) * 1024 + k0 + c * 8;
      async16(&lds[(unsigned)(gs & ~63) * 8], src);
    }
    __syncthreads();

#pragma unroll
    for (int ks = 0; ks < 2; ++ks) {
      bf16x8 af[4][2], bfr[2][2];
#pragma unroll
      for (int fm = 0; fm < 4; ++fm) {
        int rowL = wr + fm * 16 + cl;
        int idx = rowL * 64 + (((4 * ks + g) ^ (rowL & 7)) * 8);
        af[fm][0] = *(const bf16x8*)&lds[idx];
        af[fm][1] = *(const bf16x8*)&lds[8192 + idx];
      }
#pragma unroll
      for (int fn = 0; fn < 2; ++fn) {
        int rowL = wc + fn * 16 + cl;
        int idx = rowL * 64 + (((4 * ks + g) ^ (rowL & 7)) * 8);
        bfr[fn][0] = *(const bf16x8*)&lds[16384 + idx];
        bfr[fn][1] = *(const bf16x8*)&lds[24576 + idx];
      }
#pragma unroll
      for (int fm = 0; fm < 4; ++fm)
#pragma unroll
        for (int fn = 0; fn < 2; ++fn) {
          acc[fm][fn] = MFMA(af[fm][0], bfr[fn][0], acc[fm][fn]);
          acc[fm][fn] = MFMA(af[fm][0], bfr[fn][1], acc[fm][fn]);
          acc[fm][fn] = MFMA(af[fm][1], bfr[fn][0], acc[fm][fn]);
        }
    }
    __syncthreads();
  }

#pragma unroll
  for (int fm = 0; fm < 4; ++fm) {
#pragma unroll
    for (int fn = 0; fn < 2; ++fn) {
      int cc = n0 + wc + fn * 16 + cl;
      float bv = bias[cc];
      f32x4 a = acc[fm][fn];
#pragma unroll
      for (int r = 0; r < 4; ++r) {
        int rr = m0 + wr + fm * 16 + g * 4 + r;
        float v = a[r] + bv;
        if (MODE == 0) {
          int seg = cc >> 10, cm = cc & 1023;
          int h = cm >> 6, d = cm & 63;
          int b = rr >> 11, n = rr & 2047;
          int bh = b * 16 + h;
          if (seg == 0) {
            v *= 0.1803368801111204f;  // SCALE * log2(e): exp2-domain softmax
            u16 hh = f2bf(v), ll = f2bf(v - bf2f(hh));
            int o = (bh * 2048 + n) * 64 + d;
            oQh[o] = hh; oQl[o] = ll;
          } else if (seg == 1) {
            u16 hh = f2bf(v), ll = f2bf(v - bf2f(hh));
            int o = (bh * 2048 + n) * 64 + d;
            oKh[o] = hh; oKl[o] = ll;
          } else {
            u16 hh = f2bf(v), ll = f2bf(v - bf2f(hh));
            int o = (bh * 64 + d) * 2048 + n;  // V stored transposed [bh][d][n]
            oVh[o] = hh; oVl[o] = ll;
          }
        } else {
          fout[rr * 1024 + cc] = v;
        }
      }
    }
  }
}

// ---------------- flash attention (swapped QK^T, base-2, double-buffered) ----
// grid 512, 8 waves x 16 q-rows = 128 q-rows/block. KV tile = 64 keys.
// LDS: 2 x 32KB K/V double-buffer + 8 x 2KB per-wave P = 80KB.
// 2 blocks/CU x 512 threads = 16 waves/CU.
__global__ __launch_bounds__(512, 4) void k_attn(
    const u16* __restrict__ Qh, const u16* __restrict__ Ql,
    const u16* __restrict__ Kh, const u16* __restrict__ Kl,
    const u16* __restrict__ Vh, const u16* __restrict__ Vl,
    u16* __restrict__ Oh, u16* __restrict__ Ol) {
  // LDS u16 units, per buffer p (base = p*16384): K_h @0 [64 key][64 d],
  // K_l @4096, Vt_h @8192 [64 d][64 key], Vt_l @12288.
  // P per wave @32768 + w*1024 ([16 q][64 k]). Total 40960 u16 = 80KB.
  __shared__ u16 lds[40960];
  const int t = threadIdx.x, w = t >> 6, lane = t & 63, g = lane >> 4, cl = lane & 15;
  int bid = (blockIdx.x & 7) * 64 + (blockIdx.x >> 3);  // same-bh blocks -> same XCD
  const int bh = bid >> 4, qt = bid & 15;
  const int n0 = qt * 128;
  const int PH = 32768 + w * 1024;

  // Q fragments (B operand; pre-scaled by SCALE*log2e). Wave owns rows
  // n0 + w*16 + 0..15.
  bf16x8 qfh[2], qfl[2];
  {
    int rg = bh * 2048 + n0 + w * 16 + cl;
#pragma unroll
    for (int ks = 0; ks < 2; ++ks) {
      qfh[ks] = *(const bf16x8*)&Qh[rg * 64 + ks * 32 + g * 8];
      qfl[ks] = *(const bf16x8*)&Ql[rg * 64 + ks * 32 + g * 8];
    }
  }

  f32x4 o[4] = {};
  float mrun = -1e30f, lrun = 0.f;
  const int bsrc = (lane & 48) | ((lane >> 2) & 12);  // lane with cl = 4g (same g)
  const int swz = (cl & 7) << 3;

#define STAGE_KV(kt_, pbase_)                                              \
  {                                                                        \
    const int kt__ = (kt_);                                                \
    const unsigned pb__ = (pbase_);                                        \
    _Pragma("unroll") for (int j = 0; j < 4; ++j) {                        \
      int gs = j * 512 + t;                                                \
      int tensor = gs >> 9, s = gs & 511, row = s >> 3;                    \
      int c = (s & 7) ^ (row & 7);                                         \
      const u16* src;                                                      \
      if (tensor == 0)                                                     \
        src = Kh + (bh * 2048 + kt__ * 64 + row) * 64 + c * 8;             \
      else if (tensor == 1)                                                \
        src = Kl + (bh * 2048 + kt__ * 64 + row) * 64 + c * 8;             \
      else if (tensor == 2)                                                \
        src = Vh + (bh * 64 + row) * 2048 + kt__ * 64 + c * 8;             \
      else                                                                 \
        src = Vl + (bh * 64 + row) * 2048 + kt__ * 64 + c * 8;             \
      async16(&lds[pb__ + (unsigned)(gs & ~63) * 8], src);                 \
    }                                                                      \
  }

  STAGE_KV(0, 0u);
  __syncthreads();
  unsigned p = 0;

  for (int kt = 0; kt < 32; ++kt) {
    const unsigned base = p * 16384u;
    if (kt < 31) STAGE_KV(kt + 1, base ^ 16384u);

    // S^T = K.Q (3-term split): st[fn][r] = S[q=cl][k=fn*16+4g+r], log2 units
    f32x4 st[4] = {};
    __builtin_amdgcn_s_setprio(1);
#pragma unroll
    for (int fn = 0; fn < 4; ++fn) {
      int krow = fn * 16 + cl;
#pragma unroll
      for (int ks = 0; ks < 2; ++ks) {
        unsigned idx = base + krow * 64 + (((4 * ks + g) ^ (krow & 7)) * 8);
        bf16x8 kfh = *(const bf16x8*)&lds[idx];
        bf16x8 kfl = *(const bf16x8*)&lds[4096 + idx];
        st[fn] = MFMA(kfh, qfh[ks], st[fn]);
        st[fn] = MFMA(kfl, qfh[ks], st[fn]);
        st[fn] = MFMA(kfh, qfl[ks], st[fn]);
      }
    }
    __builtin_amdgcn_s_setprio(0);

    // online softmax (base 2), lane-owns-row, defer-max rescale
    float pmax;
    {
      float a = fmaxf(fmaxf(st[0][0], st[0][1]), fmaxf(st[0][2], st[0][3]));
      float b = fmaxf(fmaxf(st[1][0], st[1][1]), fmaxf(st[1][2], st[1][3]));
      float c = fmaxf(fmaxf(st[2][0], st[2][1]), fmaxf(st[2][2], st[2][3]));
      float d = fmaxf(fmaxf(st[3][0], st[3][1]), fmaxf(st[3][2], st[3][3]));
      pmax = fmaxf(fmaxf(a, b), fmaxf(c, d));
    }
    pmax = fmaxf(pmax, __shfl_xor(pmax, 16));
    pmax = fmaxf(pmax, __shfl_xor(pmax, 32));
    if (__any(pmax > mrun + 8.0f)) {
      float mnew = fmaxf(mrun, pmax);
      float esc = __builtin_amdgcn_exp2f(mrun - mnew);
      mrun = mnew;
      lrun *= esc;
      float e0 = __shfl(esc, bsrc), e1 = __shfl(esc, bsrc | 1);
      float e2 = __shfl(esc, bsrc | 2), e3 = __shfl(esc, bsrc | 3);
#pragma unroll
      for (int fd = 0; fd < 4; ++fd) {
        o[fd][0] *= e0; o[fd][1] *= e1;
        o[fd][2] *= e2; o[fd][3] *= e3;
      }
    }
    float psum = 0.f;
    unsigned upk[4][2];
#pragma unroll
    for (int fn = 0; fn < 4; ++fn) {
      float p0 = __builtin_amdgcn_exp2f(st[fn][0] - mrun);
      float p1 = __builtin_amdgcn_exp2f(st[fn][1] - mrun);
      float p2 = __builtin_amdgcn_exp2f(st[fn][2] - mrun);
      float p3 = __builtin_amdgcn_exp2f(st[fn][3] - mrun);
      psum += (p0 + p1) + (p2 + p3);
      upk[fn][0] = pack_bf2(p0, p1);
      upk[fn][1] = pack_bf2(p2, p3);
    }
    psum += __shfl_xor(psum, 16);
    psum += __shfl_xor(psum, 32);
    lrun += psum;

    // write P rows (q = cl, keys fn*16+4g+0..3), XOR-swizzled, private region
#pragma unroll
    for (int fn = 0; fn < 4; ++fn) {
      int addr = (cl * 64 + fn * 16 + 4 * g) ^ swz;
      *(uint2*)&lds[PH + addr] = make_uint2(upk[fn][0], upk[fn][1]);
    }

    // P A-fragments back (same wave, no barrier)
    bf16x8 pa[2];
#pragma unroll
    for (int ks = 0; ks < 2; ++ks) {
      int addr = (cl * 64 + ks * 32 + 8 * g) ^ swz;
      pa[ks] = *(const bf16x8*)&lds[PH + addr];
    }

    // O += P.V (2-term: ph*vh + ph*vl)
    __builtin_amdgcn_s_setprio(1);
#pragma unroll
    for (int fd = 0; fd < 4; ++fd) {
      int vrow = fd * 16 + cl;
#pragma unroll
      for (int ks = 0; ks < 2; ++ks) {
        unsigned idx = base + 8192 + vrow * 64 + (((4 * ks + g) ^ (vrow & 7)) * 8);
        bf16x8 vfh = *(const bf16x8*)&lds[idx];
        bf16x8 vfl = *(const bf16x8*)&lds[4096 + idx];
        o[fd] = MFMA(pa[ks], vfh, o[fd]);
        o[fd] = MFMA(pa[ks], vfl, o[fd]);
      }
    }
    __builtin_amdgcn_s_setprio(0);
    __syncthreads();
    p ^= 1;
  }
#undef STAGE_KV

  // normalize + write O (split, [token][h*64+d] layout for proj GEMM)
  const int b = bh >> 4, h = bh & 15;
  float l0 = __shfl(lrun, bsrc), l1 = __shfl(lrun, bsrc | 1);
  float l2 = __shfl(lrun, bsrc | 2), l3 = __shfl(lrun, bsrc | 3);
  float inv[4] = {1.0f / l0, 1.0f / l1, 1.0f / l2, 1.0f / l3};
#pragma unroll
  for (int fd = 0; fd < 4; ++fd)
#pragma unroll
    for (int r = 0; r < 4; ++r) {
      float v = o[fd][r] * inv[r];
      u16 hh = f2bf(v), ll = f2bf(v - bf2f(hh));
      int rowg = b * 2048 + n0 + w * 16 + 4 * g + r;
      int colg = h * 64 + fd * 16 + cl;
      Oh[rowg * 1024 + colg] = hh;
      Ol[rowg * 1024 + colg] = ll;
    }
}

extern "C" void kernel_launch(void* const* d_in, const int* in_sizes, int n_in,
                              void* d_out, int out_size, void* d_ws, size_t ws_size,
                              hipStream_t stream) {
  const float* x  = (const float*)d_in[0];
  const float* Wq = (const float*)d_in[1];
  const float* bq = (const float*)d_in[2];
  const float* Wp = (const float*)d_in[3];
  const float* bp = (const float*)d_in[4];
  float* out = (float*)d_out;
  char* ws = (char*)d_ws;

  u16* Xh  = (u16*)(ws + 0);         // also Oh
  u16* Xl  = (u16*)(ws + 8388608);   // also Ol
  u16* Wqh = (u16*)(ws + 16777216);
  u16* Wql = (u16*)(ws + 23068672);
  u16* Wph = (u16*)(ws + 29360128);
  u16* Wpl = (u16*)(ws + 31457280);
  u16* Qh  = (u16*)(ws + 33554432);
  u16* Ql  = (u16*)(ws + 41943040);
  u16* Kh  = (u16*)(ws + 50331648);
  u16* Kl  = (u16*)(ws + 58720256);
  u16* Vh  = (u16*)(ws + 67108864);
  u16* Vl  = (u16*)(ws + 75497472);  // end 83886080 (80MB)

  k_split_all<<<8192, 256, 0, stream>>>(x, Wq, Wp, Xh, Xl, Wqh, Wql, Wph, Wpl);

  k_gemm<0><<<32 * 24, 512, 0, stream>>>(Xh, Xl, Wqh, Wql, bq,
                                         Qh, Ql, Kh, Kl, Vh, Vl, nullptr, 24);
  k_attn<<<512, 512, 0, stream>>>(Qh, Ql, Kh, Kl, Vh, Vl, Xh, Xl);
  k_gemm<1><<<32 * 8, 512, 0, stream>>>(Xh, Xl, Wph, Wpl, bp,
                                        nullptr, nullptr, nullptr, nullptr,
                                        nullptr, nullptr, out, 8);
}

// Round 8
// 237.039 us; speedup vs baseline: 1.1229x; 1.0388x over previous
//
#include <hip/hip_runtime.h>
#include <hip/hip_bf16.h>

// MHA forward: qkv GEMM (bf16x3 split MFMA) -> flash attention -> proj GEMM.
// B=2, N=2048, C=1024, H=16, D=64.
// R8: GEMM -> double-buffered BK=64 (128KB LDS, prefetch kt+1 issued before
//     compute of kt, one barrier/iter), 8 waves, setprio around MFMA.
//     Grids 768/256 = exact CU multiples (no tail). attn/split unchanged (R7).

typedef unsigned short u16;
typedef __attribute__((ext_vector_type(8))) short bf16x8;
typedef __attribute__((ext_vector_type(4))) float f32x4;

#define DEV static __device__ __forceinline__
#define MFMA(a, b, c) __builtin_amdgcn_mfma_f32_16x16x32_bf16(a, b, c, 0, 0, 0)

DEV u16 f2bf(float f) {
  unsigned u = __float_as_uint(f);
  return (u16)((u + 0x7fffu + ((u >> 16) & 1u)) >> 16);  // RNE
}
DEV float bf2f(u16 h) { return __uint_as_float(((unsigned)h) << 16); }

DEV unsigned pack_bf2(float a, float b) {
  __hip_bfloat162 h2 = __float22bfloat162_rn(make_float2(a, b));
  return *reinterpret_cast<unsigned*>(&h2);
}

DEV void async16(u16* dst, const u16* src) {
  __builtin_amdgcn_global_load_lds(
      (const __attribute__((address_space(1))) unsigned int*)(const void*)src,
      (__attribute__((address_space(3))) unsigned int*)(void*)dst, 16, 0, 0);
}

// ---------------- split fp32 -> bf16 hi/lo (all three inputs, one launch) ----
__global__ __launch_bounds__(256) void k_split_all(
    const float* __restrict__ x, const float* __restrict__ wq,
    const float* __restrict__ wp, u16* __restrict__ xh, u16* __restrict__ xl,
    u16* __restrict__ wqh, u16* __restrict__ wql, u16* __restrict__ wph,
    u16* __restrict__ wpl) {
  int i = blockIdx.x * 256 + threadIdx.x;
  const float* src;
  u16 *dh, *dl;
  int off;
  if (i < 1048576) { src = x;  dh = xh;  dl = xl;  off = i; }
  else if (i < 1835008) { src = wq; dh = wqh; dl = wql; off = i - 1048576; }
  else { src = wp; dh = wph; dl = wpl; off = i - 1835008; }
  float4 v = ((const float4*)src)[off];
  ushort4 h, l;
  h.x = f2bf(v.x); l.x = f2bf(v.x - bf2f(h.x));
  h.y = f2bf(v.y); l.y = f2bf(v.y - bf2f(h.y));
  h.z = f2bf(v.z); l.z = f2bf(v.z - bf2f(h.z));
  h.w = f2bf(v.w); l.w = f2bf(v.w - bf2f(h.w));
  ((ushort4*)dh)[off] = h;
  ((ushort4*)dl)[off] = l;
}

// ---------------- GEMM: C[M][N] = A[M][1024] . B[N][1024]^T + bias ----------------
// 128x128 tile, BK=64, 8 waves (2x4 grid, 64x32 per wave), bf16x3 split.
// Double-buffered: prefetch kt+1 into buf^1 before computing buf; 1 barrier/iter.
template <int MODE>
__global__ __launch_bounds__(512) void k_gemm(
    const u16* __restrict__ Ah_g, const u16* __restrict__ Al_g,
    const u16* __restrict__ Bh_g, const u16* __restrict__ Bl_g,
    const float* __restrict__ bias,
    u16* __restrict__ oQh, u16* __restrict__ oQl,
    u16* __restrict__ oKh, u16* __restrict__ oKl,
    u16* __restrict__ oVh, u16* __restrict__ oVl,
    float* __restrict__ fout, int nbn) {
  // 128KB: 2 buffers x (Ah[128][64] @0, Al @8192, Bh @16384, Bl @24576) u16.
  __shared__ u16 lds[65536];
  const int t = threadIdx.x;
  const int lane = t & 63, g = lane >> 4, cl = lane & 15;
  const int w = t >> 6;
  const int mi = blockIdx.x / nbn, ni = blockIdx.x % nbn;
  const int m0 = mi * 128, n0 = ni * 128;
  const int wr = (w >> 2) * 64, wc = (w & 3) * 32;

  f32x4 acc[4][2] = {};

#define STAGE_AB(kt_, pb_)                                                  \
  {                                                                         \
    const int k0__ = (kt_) * 64;                                            \
    const unsigned pb__ = (pb_);                                            \
    _Pragma("unroll") for (int j = 0; j < 8; ++j) {                         \
      int gs = j * 512 + t;                                                 \
      int tensor = gs >> 10;                                                \
      int s = gs & 1023;                                                    \
      int row = s >> 3;                                                     \
      int c = (s & 7) ^ (row & 7);                                          \
      const u16* src;                                                       \
      if (tensor == 0)      src = Ah_g + (m0 + row) * 1024 + k0__ + c * 8;  \
      else if (tensor == 1) src = Al_g + (m0 + row) * 1024 + k0__ + c * 8;  \
      else if (tensor == 2) src = Bh_g + (n0 + row) * 1024 + k0__ + c * 8;  \
      else                  src = Bl_g + (n0 + row) * 1024 + k0__ + c * 8;  \
      async16(&lds[pb__ + (unsigned)(gs & ~63) * 8], src);                  \
    }                                                                       \
  }

  STAGE_AB(0, 0u);
  __syncthreads();
  unsigned p = 0;

  for (int kt = 0; kt < 16; ++kt) {
    const unsigned base = p * 32768u;
    if (kt < 15) STAGE_AB(kt + 1, base ^ 32768u);

#pragma unroll
    for (int ks = 0; ks < 2; ++ks) {
      bf16x8 af[4][2], bfr[2][2];
#pragma unroll
      for (int fm = 0; fm < 4; ++fm) {
        int rowL = wr + fm * 16 + cl;
        unsigned idx = base + rowL * 64 + (((4 * ks + g) ^ (rowL & 7)) * 8);
        af[fm][0] = *(const bf16x8*)&lds[idx];
        af[fm][1] = *(const bf16x8*)&lds[8192 + idx];
      }
#pragma unroll
      for (int fn = 0; fn < 2; ++fn) {
        int rowL = wc + fn * 16 + cl;
        unsigned idx = base + rowL * 64 + (((4 * ks + g) ^ (rowL & 7)) * 8);
        bfr[fn][0] = *(const bf16x8*)&lds[16384 + idx];
        bfr[fn][1] = *(const bf16x8*)&lds[24576 + idx];
      }
      __builtin_amdgcn_s_setprio(1);
#pragma unroll
      for (int fm = 0; fm < 4; ++fm)
#pragma unroll
        for (int fn = 0; fn < 2; ++fn) {
          acc[fm][fn] = MFMA(af[fm][0], bfr[fn][0], acc[fm][fn]);
          acc[fm][fn] = MFMA(af[fm][0], bfr[fn][1], acc[fm][fn]);
          acc[fm][fn] = MFMA(af[fm][1], bfr[fn][0], acc[fm][fn]);
        }
      __builtin_amdgcn_s_setprio(0);
    }
    __syncthreads();
    p ^= 1;
  }
#undef STAGE_AB

  // epilogue
#pragma unroll
  for (int fm = 0; fm < 4; ++fm) {
#pragma unroll
    for (int fn = 0; fn < 2; ++fn) {
      int cc = n0 + wc + fn * 16 + cl;
      float bv = bias[cc];
      f32x4 a = acc[fm][fn];
#pragma unroll
      for (int r = 0; r < 4; ++r) {
        int rr = m0 + wr + fm * 16 + g * 4 + r;
        float v = a[r] + bv;
        if (MODE == 0) {
          int seg = cc >> 10, cm = cc & 1023;
          int h = cm >> 6, d = cm & 63;
          int b = rr >> 11, n = rr & 2047;
          int bh = b * 16 + h;
          if (seg == 0) {
            v *= 0.1803368801111204f;  // SCALE * log2(e): exp2-domain softmax
            u16 hh = f2bf(v), ll = f2bf(v - bf2f(hh));
            int o = (bh * 2048 + n) * 64 + d;
            oQh[o] = hh; oQl[o] = ll;
          } else if (seg == 1) {
            u16 hh = f2bf(v), ll = f2bf(v - bf2f(hh));
            int o = (bh * 2048 + n) * 64 + d;
            oKh[o] = hh; oKl[o] = ll;
          } else {
            u16 hh = f2bf(v), ll = f2bf(v - bf2f(hh));
            int o = (bh * 64 + d) * 2048 + n;  // V stored transposed [bh][d][n]
            oVh[o] = hh; oVl[o] = ll;
          }
        } else {
          fout[rr * 1024 + cc] = v;
        }
      }
    }
  }
}

// ---------------- flash attention (swapped QK^T, base-2, double-buffered) ----
// grid 512, 8 waves x 16 q-rows = 128 q-rows/block. KV tile = 64 keys.
// LDS: 2 x 32KB K/V double-buffer + 8 x 2KB per-wave P = 80KB.
__global__ __launch_bounds__(512, 4) void k_attn(
    const u16* __restrict__ Qh, const u16* __restrict__ Ql,
    const u16* __restrict__ Kh, const u16* __restrict__ Kl,
    const u16* __restrict__ Vh, const u16* __restrict__ Vl,
    u16* __restrict__ Oh, u16* __restrict__ Ol) {
  __shared__ u16 lds[40960];
  const int t = threadIdx.x, w = t >> 6, lane = t & 63, g = lane >> 4, cl = lane & 15;
  int bid = (blockIdx.x & 7) * 64 + (blockIdx.x >> 3);  // same-bh blocks -> same XCD
  const int bh = bid >> 4, qt = bid & 15;
  const int n0 = qt * 128;
  const int PH = 32768 + w * 1024;

  bf16x8 qfh[2], qfl[2];
  {
    int rg = bh * 2048 + n0 + w * 16 + cl;
#pragma unroll
    for (int ks = 0; ks < 2; ++ks) {
      qfh[ks] = *(const bf16x8*)&Qh[rg * 64 + ks * 32 + g * 8];
      qfl[ks] = *(const bf16x8*)&Ql[rg * 64 + ks * 32 + g * 8];
    }
  }

  f32x4 o[4] = {};
  float mrun = -1e30f, lrun = 0.f;
  const int bsrc = (lane & 48) | ((lane >> 2) & 12);  // lane with cl = 4g (same g)
  const int swz = (cl & 7) << 3;

#define STAGE_KV(kt_, pbase_)                                              \
  {                                                                        \
    const int kt__ = (kt_);                                                \
    const unsigned pb__ = (pbase_);                                        \
    _Pragma("unroll") for (int j = 0; j < 4; ++j) {                        \
      int gs = j * 512 + t;                                                \
      int tensor = gs >> 9, s = gs & 511, row = s >> 3;                    \
      int c = (s & 7) ^ (row & 7);                                         \
      const u16* src;                                                      \
      if (tensor == 0)                                                     \
        src = Kh + (bh * 2048 + kt__ * 64 + row) * 64 + c * 8;             \
      else if (tensor == 1)                                                \
        src = Kl + (bh * 2048 + kt__ * 64 + row) * 64 + c * 8;             \
      else if (tensor == 2)                                                \
        src = Vh + (bh * 64 + row) * 2048 + kt__ * 64 + c * 8;             \
      else                                                                 \
        src = Vl + (bh * 64 + row) * 2048 + kt__ * 64 + c * 8;             \
      async16(&lds[pb__ + (unsigned)(gs & ~63) * 8], src);                 \
    }                                                                      \
  }

  STAGE_KV(0, 0u);
  __syncthreads();
  unsigned p = 0;

  for (int kt = 0; kt < 32; ++kt) {
    const unsigned base = p * 16384u;
    if (kt < 31) STAGE_KV(kt + 1, base ^ 16384u);

    f32x4 st[4] = {};
    __builtin_amdgcn_s_setprio(1);
#pragma unroll
    for (int fn = 0; fn < 4; ++fn) {
      int krow = fn * 16 + cl;
#pragma unroll
      for (int ks = 0; ks < 2; ++ks) {
        unsigned idx = base + krow * 64 + (((4 * ks + g) ^ (krow & 7)) * 8);
        bf16x8 kfh = *(const bf16x8*)&lds[idx];
        bf16x8 kfl = *(const bf16x8*)&lds[4096 + idx];
        st[fn] = MFMA(kfh, qfh[ks], st[fn]);
        st[fn] = MFMA(kfl, qfh[ks], st[fn]);
        st[fn] = MFMA(kfh, qfl[ks], st[fn]);
      }
    }
    __builtin_amdgcn_s_setprio(0);

    float pmax;
    {
      float a = fmaxf(fmaxf(st[0][0], st[0][1]), fmaxf(st[0][2], st[0][3]));
      float b = fmaxf(fmaxf(st[1][0], st[1][1]), fmaxf(st[1][2], st[1][3]));
      float c = fmaxf(fmaxf(st[2][0], st[2][1]), fmaxf(st[2][2], st[2][3]));
      float d = fmaxf(fmaxf(st[3][0], st[3][1]), fmaxf(st[3][2], st[3][3]));
      pmax = fmaxf(fmaxf(a, b), fmaxf(c, d));
    }
    pmax = fmaxf(pmax, __shfl_xor(pmax, 16));
    pmax = fmaxf(pmax, __shfl_xor(pmax, 32));
    if (__any(pmax > mrun + 8.0f)) {
      float mnew = fmaxf(mrun, pmax);
      float esc = __builtin_amdgcn_exp2f(mrun - mnew);
      mrun = mnew;
      lrun *= esc;
      float e0 = __shfl(esc, bsrc), e1 = __shfl(esc, bsrc | 1);
      float e2 = __shfl(esc, bsrc | 2), e3 = __shfl(esc, bsrc | 3);
#pragma unroll
      for (int fd = 0; fd < 4; ++fd) {
        o[fd][0] *= e0; o[fd][1] *= e1;
        o[fd][2] *= e2; o[fd][3] *= e3;
      }
    }
    float psum = 0.f;
    unsigned upk[4][2];
#pragma unroll
    for (int fn = 0; fn < 4; ++fn) {
      float p0 = __builtin_amdgcn_exp2f(st[fn][0] - mrun);
      float p1 = __builtin_amdgcn_exp2f(st[fn][1] - mrun);
      float p2 = __builtin_amdgcn_exp2f(st[fn][2] - mrun);
      float p3 = __builtin_amdgcn_exp2f(st[fn][3] - mrun);
      psum += (p0 + p1) + (p2 + p3);
      upk[fn][0] = pack_bf2(p0, p1);
      upk[fn][1] = pack_bf2(p2, p3);
    }
    psum += __shfl_xor(psum, 16);
    psum += __shfl_xor(psum, 32);
    lrun += psum;

#pragma unroll
    for (int fn = 0; fn < 4; ++fn) {
      int addr = (cl * 64 + fn * 16 + 4 * g) ^ swz;
      *(uint2*)&lds[PH + addr] = make_uint2(upk[fn][0], upk[fn][1]);
    }

    bf16x8 pa[2];
#pragma unroll
    for (int ks = 0; ks < 2; ++ks) {
      int addr = (cl * 64 + ks * 32 + 8 * g) ^ swz;
      pa[ks] = *(const bf16x8*)&lds[PH + addr];
    }

    __builtin_amdgcn_s_setprio(1);
#pragma unroll
    for (int fd = 0; fd < 4; ++fd) {
      int vrow = fd * 16 + cl;
#pragma unroll
      for (int ks = 0; ks < 2; ++ks) {
        unsigned idx = base + 8192 + vrow * 64 + (((4 * ks + g) ^ (vrow & 7)) * 8);
        bf16x8 vfh = *(const bf16x8*)&lds[idx];
        bf16x8 vfl = *(const bf16x8*)&lds[4096 + idx];
        o[fd] = MFMA(pa[ks], vfh, o[fd]);
        o[fd] = MFMA(pa[ks], vfl, o[fd]);
      }
    }
    __builtin_amdgcn_s_setprio(0);
    __syncthreads();
    p ^= 1;
  }
#undef STAGE_KV

  const int b = bh >> 4, h = bh & 15;
  float l0 = __shfl(lrun, bsrc), l1 = __shfl(lrun, bsrc | 1);
  float l2 = __shfl(lrun, bsrc | 2), l3 = __shfl(lrun, bsrc | 3);
  float inv[4] = {1.0f / l0, 1.0f / l1, 1.0f / l2, 1.0f / l3};
#pragma unroll
  for (int fd = 0; fd < 4; ++fd)
#pragma unroll
    for (int r = 0; r < 4; ++r) {
      float v = o[fd][r] * inv[r];
      u16 hh = f2bf(v), ll = f2bf(v - bf2f(hh));
      int rowg = b * 2048 + n0 + w * 16 + 4 * g + r;
      int colg = h * 64 + fd * 16 + cl;
      Oh[rowg * 1024 + colg] = hh;
      Ol[rowg * 1024 + colg] = ll;
    }
}

extern "C" void kernel_launch(void* const* d_in, const int* in_sizes, int n_in,
                              void* d_out, int out_size, void* d_ws, size_t ws_size,
                              hipStream_t stream) {
  const float* x  = (const float*)d_in[0];
  const float* Wq = (const float*)d_in[1];
  const float* bq = (const float*)d_in[2];
  const float* Wp = (const float*)d_in[3];
  const float* bp = (const float*)d_in[4];
  float* out = (float*)d_out;
  char* ws = (char*)d_ws;

  u16* Xh  = (u16*)(ws + 0);         // also Oh
  u16* Xl  = (u16*)(ws + 8388608);   // also Ol
  u16* Wqh = (u16*)(ws + 16777216);
  u16* Wql = (u16*)(ws + 23068672);
  u16* Wph = (u16*)(ws + 29360128);
  u16* Wpl = (u16*)(ws + 31457280);
  u16* Qh  = (u16*)(ws + 33554432);
  u16* Ql  = (u16*)(ws + 41943040);
  u16* Kh  = (u16*)(ws + 50331648);
  u16* Kl  = (u16*)(ws + 58720256);
  u16* Vh  = (u16*)(ws + 67108864);
  u16* Vl  = (u16*)(ws + 75497472);  // end 83886080 (80MB)

  k_split_all<<<8192, 256, 0, stream>>>(x, Wq, Wp, Xh, Xl, Wqh, Wql, Wph, Wpl);

  k_gemm<0><<<32 * 24, 512, 0, stream>>>(Xh, Xl, Wqh, Wql, bq,
                                         Qh, Ql, Kh, Kl, Vh, Vl, nullptr, 24);
  k_attn<<<512, 512, 0, stream>>>(Qh, Ql, Kh, Kl, Vh, Vl, Xh, Xl);
  k_gemm<1><<<32 * 8, 512, 0, stream>>>(Xh, Xl, Wph, Wpl, bp,
                                        nullptr, nullptr, nullptr, nullptr,
                                        nullptr, nullptr, out, 8);
}

// Round 9
// 219.613 us; speedup vs baseline: 1.2120x; 1.0793x over previous
//
#include <hip/hip_runtime.h>

// MHA forward: qkv GEMM -> flash attention -> proj GEMM. B=2,N=2048,C=1024,H=16,D=64.
// R9: numerics switched bf16x3 -> fp16x2 (A = hi+lo fp16 pair (22-bit), B = fp16 hi
//     only; dropped cross-term ~2^-12 relative). GEMM: 3 staged tensors, 48KB LDS,
//     serial stage (R6 structure), 8 waves x (32x64) tiles, 3 blocks/CU. attn: 2-term
//     QK^T (Q hi-only), fp16 P (more precise than bf16). SCALE*log2e folded into Q.

typedef unsigned short u16;
typedef __attribute__((ext_vector_type(8))) _Float16 f16x8;
typedef __attribute__((ext_vector_type(4))) float f32x4;

#define DEV static __device__ __forceinline__
#define MFMA16(a, b, c) __builtin_amdgcn_mfma_f32_16x16x32_f16(a, b, c, 0, 0, 0)

DEV u16 f2h(float f) { _Float16 h = (_Float16)f; return __builtin_bit_cast(u16, h); }
DEV float h2f(u16 u) { return (float)__builtin_bit_cast(_Float16, u); }
DEV unsigned pack_h2(float a, float b) {
  return (unsigned)f2h(a) | ((unsigned)f2h(b) << 16);
}

DEV void async16(u16* dst, const u16* src) {
  __builtin_amdgcn_global_load_lds(
      (const __attribute__((address_space(1))) unsigned int*)(const void*)src,
      (__attribute__((address_space(3))) unsigned int*)(void*)dst, 16, 0, 0);
}

// ---------------- split fp32 -> fp16 hi(/lo) ----------------
// x -> pair (A-operand); wq, wp -> hi only (B-operand, lo never used).
__global__ __launch_bounds__(256) void k_split_all(
    const float* __restrict__ x, const float* __restrict__ wq,
    const float* __restrict__ wp, u16* __restrict__ xh, u16* __restrict__ xl,
    u16* __restrict__ wqh, u16* __restrict__ wph) {
  int i = blockIdx.x * 256 + threadIdx.x;
  if (i < 1048576) {
    float4 v = ((const float4*)x)[i];
    ushort4 h, l;
    h.x = f2h(v.x); l.x = f2h(v.x - h2f(h.x));
    h.y = f2h(v.y); l.y = f2h(v.y - h2f(h.y));
    h.z = f2h(v.z); l.z = f2h(v.z - h2f(h.z));
    h.w = f2h(v.w); l.w = f2h(v.w - h2f(h.w));
    ((ushort4*)xh)[i] = h;
    ((ushort4*)xl)[i] = l;
  } else {
    const float* src;
    u16* dh;
    int off;
    if (i < 1835008) { src = wq; dh = wqh; off = i - 1048576; }
    else             { src = wp; dh = wph; off = i - 1835008; }
    float4 v = ((const float4*)src)[off];
    ushort4 h;
    h.x = f2h(v.x); h.y = f2h(v.y); h.z = f2h(v.z); h.w = f2h(v.w);
    ((ushort4*)dh)[off] = h;
  }
}

// ---------------- GEMM: C[M][N] = A[M][1024] . B[N][1024]^T + bias ----------------
// 128x128 tile, BK=64, 8 waves (4x2 grid, 32x64 per wave), fp16x2 split
// (ah*bh + al*bh). Serial stage -> barrier -> compute -> barrier; 48KB LDS.
template <int MODE>
__global__ __launch_bounds__(512) void k_gemm(
    const u16* __restrict__ Ah_g, const u16* __restrict__ Al_g,
    const u16* __restrict__ Bh_g, const float* __restrict__ bias,
    u16* __restrict__ oQh,
    u16* __restrict__ oKh, u16* __restrict__ oKl,
    u16* __restrict__ oVh, u16* __restrict__ oVl,
    float* __restrict__ fout, int nbn) {
  // LDS 48KB: Ah[128][64] @0, Al @8192, Bh @16384 (u16 units).
  __shared__ u16 lds[24576];
  const int t = threadIdx.x;
  const int lane = t & 63, g = lane >> 4, cl = lane & 15;
  const int w = t >> 6;
  const int mi = blockIdx.x / nbn, ni = blockIdx.x % nbn;
  const int m0 = mi * 128, n0 = ni * 128;
  const int wr = (w >> 1) * 32, wc = (w & 1) * 64;

  f32x4 acc[2][4] = {};

  for (int kt = 0; kt < 16; ++kt) {
    const int k0 = kt * 64;
    // stage 3 tensors x 1024 chunks of 16B; linear LDS dest, swizzled source
#pragma unroll
    for (int j = 0; j < 6; ++j) {
      int gs = j * 512 + t;
      int tensor = gs >> 10;
      int s = gs & 1023;
      int row = s >> 3;
      int c = (s & 7) ^ (row & 7);
      const u16* src;
      if (tensor == 0)      src = Ah_g + (m0 + row) * 1024 + k0 + c * 8;
      else if (tensor == 1) src = Al_g + (m0 + row) * 1024 + k0 + c * 8;
      else                  src = Bh_g + (n0 + row) * 1024 + k0 + c * 8;
      async16(&lds[(unsigned)(gs & ~63) * 8], src);
    }
    __syncthreads();

#pragma unroll
    for (int ks = 0; ks < 2; ++ks) {
      f16x8 af[2][2], bfr[4];
#pragma unroll
      for (int fm = 0; fm < 2; ++fm) {
        int rowL = wr + fm * 16 + cl;
        unsigned idx = rowL * 64 + (((4 * ks + g) ^ (rowL & 7)) * 8);
        af[fm][0] = *(const f16x8*)&lds[idx];
        af[fm][1] = *(const f16x8*)&lds[8192 + idx];
      }
#pragma unroll
      for (int fn = 0; fn < 4; ++fn) {
        int rowL = wc + fn * 16 + cl;
        unsigned idx = rowL * 64 + (((4 * ks + g) ^ (rowL & 7)) * 8);
        bfr[fn] = *(const f16x8*)&lds[16384 + idx];
      }
#pragma unroll
      for (int fm = 0; fm < 2; ++fm)
#pragma unroll
        for (int fn = 0; fn < 4; ++fn) {
          acc[fm][fn] = MFMA16(af[fm][0], bfr[fn], acc[fm][fn]);
          acc[fm][fn] = MFMA16(af[fm][1], bfr[fn], acc[fm][fn]);
        }
    }
    __syncthreads();
  }

  // epilogue
#pragma unroll
  for (int fm = 0; fm < 2; ++fm) {
#pragma unroll
    for (int fn = 0; fn < 4; ++fn) {
      int cc = n0 + wc + fn * 16 + cl;
      float bv = bias[cc];
      f32x4 a = acc[fm][fn];
#pragma unroll
      for (int r = 0; r < 4; ++r) {
        int rr = m0 + wr + fm * 16 + g * 4 + r;
        float v = a[r] + bv;
        if (MODE == 0) {
          int seg = cc >> 10, cm = cc & 1023;
          int h = cm >> 6, d = cm & 63;
          int b = rr >> 11, n = rr & 2047;
          int bh = b * 16 + h;
          if (seg == 0) {
            v *= 0.1803368801111204f;  // SCALE * log2(e): exp2-domain softmax
            oQh[(bh * 2048 + n) * 64 + d] = f2h(v);  // Q = B-operand, hi only
          } else if (seg == 1) {
            u16 hh = f2h(v), ll = f2h(v - h2f(hh));
            int o = (bh * 2048 + n) * 64 + d;
            oKh[o] = hh; oKl[o] = ll;
          } else {
            u16 hh = f2h(v), ll = f2h(v - h2f(hh));
            int o = (bh * 64 + d) * 2048 + n;  // V stored transposed [bh][d][n]
            oVh[o] = hh; oVl[o] = ll;
          }
        } else {
          fout[rr * 1024 + cc] = v;
        }
      }
    }
  }
}

// ---------------- flash attention (swapped QK^T, base-2, double-buffered) ----
// grid 512, 8 waves x 16 q-rows = 128 q-rows/block. KV tile = 64 keys.
// S^T = (Kh+Kl).Qh (2-term); PV = Ph.(Vh+Vl) (2-term). fp16 P.
// LDS: 2 x 32KB K/V double-buffer + 8 x 2KB per-wave P = 80KB.
__global__ __launch_bounds__(512, 4) void k_attn(
    const u16* __restrict__ Qh,
    const u16* __restrict__ Kh, const u16* __restrict__ Kl,
    const u16* __restrict__ Vh, const u16* __restrict__ Vl,
    u16* __restrict__ Oh, u16* __restrict__ Ol) {
  // Per buffer p (base = p*16384 u16): K_h @0 [64 key][64 d], K_l @4096,
  // Vt_h @8192 [64 d][64 key], Vt_l @12288. P per wave @32768 + w*1024.
  __shared__ u16 lds[40960];
  const int t = threadIdx.x, w = t >> 6, lane = t & 63, g = lane >> 4, cl = lane & 15;
  int bid = (blockIdx.x & 7) * 64 + (blockIdx.x >> 3);  // same-bh blocks -> same XCD
  const int bh = bid >> 4, qt = bid & 15;
  const int n0 = qt * 128;
  const int PH = 32768 + w * 1024;

  // Q fragments (B operand, hi only; pre-scaled by SCALE*log2e)
  f16x8 qf[2];
  {
    int rg = bh * 2048 + n0 + w * 16 + cl;
#pragma unroll
    for (int ks = 0; ks < 2; ++ks)
      qf[ks] = *(const f16x8*)&Qh[rg * 64 + ks * 32 + g * 8];
  }

  f32x4 o[4] = {};
  float mrun = -1e30f, lrun = 0.f;
  const int bsrc = (lane & 48) | ((lane >> 2) & 12);  // lane with cl = 4g (same g)
  const int swz = (cl & 7) << 3;

#define STAGE_KV(kt_, pbase_)                                              \
  {                                                                        \
    const int kt__ = (kt_);                                                \
    const unsigned pb__ = (pbase_);                                        \
    _Pragma("unroll") for (int j = 0; j < 4; ++j) {                        \
      int gs = j * 512 + t;                                                \
      int tensor = gs >> 9, s = gs & 511, row = s >> 3;                    \
      int c = (s & 7) ^ (row & 7);                                         \
      const u16* src;                                                      \
      if (tensor == 0)                                                     \
        src = Kh + (bh * 2048 + kt__ * 64 + row) * 64 + c * 8;             \
      else if (tensor == 1)                                                \
        src = Kl + (bh * 2048 + kt__ * 64 + row) * 64 + c * 8;             \
      else if (tensor == 2)                                                \
        src = Vh + (bh * 64 + row) * 2048 + kt__ * 64 + c * 8;             \
      else                                                                 \
        src = Vl + (bh * 64 + row) * 2048 + kt__ * 64 + c * 8;             \
      async16(&lds[pb__ + (unsigned)(gs & ~63) * 8], src);                 \
    }                                                                      \
  }

  STAGE_KV(0, 0u);
  __syncthreads();
  unsigned p = 0;

  for (int kt = 0; kt < 32; ++kt) {
    const unsigned base = p * 16384u;
    if (kt < 31) STAGE_KV(kt + 1, base ^ 16384u);

    // S^T = K.Q (2-term): st[fn][r] = S[q=cl][k=fn*16+4g+r], log2 units
    f32x4 st[4] = {};
    __builtin_amdgcn_s_setprio(1);
#pragma unroll
    for (int fn = 0; fn < 4; ++fn) {
      int krow = fn * 16 + cl;
#pragma unroll
      for (int ks = 0; ks < 2; ++ks) {
        unsigned idx = base + krow * 64 + (((4 * ks + g) ^ (krow & 7)) * 8);
        f16x8 kfh = *(const f16x8*)&lds[idx];
        f16x8 kfl = *(const f16x8*)&lds[4096 + idx];
        st[fn] = MFMA16(kfh, qf[ks], st[fn]);
        st[fn] = MFMA16(kfl, qf[ks], st[fn]);
      }
    }
    __builtin_amdgcn_s_setprio(0);

    // online softmax (base 2), lane-owns-row, defer-max rescale
    float pmax;
    {
      float a = fmaxf(fmaxf(st[0][0], st[0][1]), fmaxf(st[0][2], st[0][3]));
      float b = fmaxf(fmaxf(st[1][0], st[1][1]), fmaxf(st[1][2], st[1][3]));
      float c = fmaxf(fmaxf(st[2][0], st[2][1]), fmaxf(st[2][2], st[2][3]));
      float d = fmaxf(fmaxf(st[3][0], st[3][1]), fmaxf(st[3][2], st[3][3]));
      pmax = fmaxf(fmaxf(a, b), fmaxf(c, d));
    }
    pmax = fmaxf(pmax, __shfl_xor(pmax, 16));
    pmax = fmaxf(pmax, __shfl_xor(pmax, 32));
    if (__any(pmax > mrun + 8.0f)) {
      float mnew = fmaxf(mrun, pmax);
      float esc = __builtin_amdgcn_exp2f(mrun - mnew);
      mrun = mnew;
      lrun *= esc;
      float e0 = __shfl(esc, bsrc), e1 = __shfl(esc, bsrc | 1);
      float e2 = __shfl(esc, bsrc | 2), e3 = __shfl(esc, bsrc | 3);
#pragma unroll
      for (int fd = 0; fd < 4; ++fd) {
        o[fd][0] *= e0; o[fd][1] *= e1;
        o[fd][2] *= e2; o[fd][3] *= e3;
      }
    }
    float psum = 0.f;
    unsigned upk[4][2];
#pragma unroll
    for (int fn = 0; fn < 4; ++fn) {
      float p0 = __builtin_amdgcn_exp2f(st[fn][0] - mrun);
      float p1 = __builtin_amdgcn_exp2f(st[fn][1] - mrun);
      float p2 = __builtin_amdgcn_exp2f(st[fn][2] - mrun);
      float p3 = __builtin_amdgcn_exp2f(st[fn][3] - mrun);
      psum += (p0 + p1) + (p2 + p3);
      upk[fn][0] = pack_h2(p0, p1);
      upk[fn][1] = pack_h2(p2, p3);
    }
    psum += __shfl_xor(psum, 16);
    psum += __shfl_xor(psum, 32);
    lrun += psum;

    // write P rows (q = cl, keys fn*16+4g+0..3), XOR-swizzled, private region
#pragma unroll
    for (int fn = 0; fn < 4; ++fn) {
      int addr = (cl * 64 + fn * 16 + 4 * g) ^ swz;
      *(uint2*)&lds[PH + addr] = make_uint2(upk[fn][0], upk[fn][1]);
    }

    // P A-fragments back (same wave, no barrier)
    f16x8 pa[2];
#pragma unroll
    for (int ks = 0; ks < 2; ++ks) {
      int addr = (cl * 64 + ks * 32 + 8 * g) ^ swz;
      pa[ks] = *(const f16x8*)&lds[PH + addr];
    }

    // O += P.V (2-term: ph*vh + ph*vl)
    __builtin_amdgcn_s_setprio(1);
#pragma unroll
    for (int fd = 0; fd < 4; ++fd) {
      int vrow = fd * 16 + cl;
#pragma unroll
      for (int ks = 0; ks < 2; ++ks) {
        unsigned idx = base + 8192 + vrow * 64 + (((4 * ks + g) ^ (vrow & 7)) * 8);
        f16x8 vfh = *(const f16x8*)&lds[idx];
        f16x8 vfl = *(const f16x8*)&lds[4096 + idx];
        o[fd] = MFMA16(pa[ks], vfh, o[fd]);
        o[fd] = MFMA16(pa[ks], vfl, o[fd]);
      }
    }
    __builtin_amdgcn_s_setprio(0);
    __syncthreads();
    p ^= 1;
  }
#undef STAGE_KV

  // normalize + write O (fp16 split pair, [token][h*64+d] layout for proj GEMM)
  const int b = bh >> 4, h = bh & 15;
  float l0 = __shfl(lrun, bsrc), l1 = __shfl(lrun, bsrc | 1);
  float l2 = __shfl(lrun, bsrc | 2), l3 = __shfl(lrun, bsrc | 3);
  float inv[4] = {1.0f / l0, 1.0f / l1, 1.0f / l2, 1.0f / l3};
#pragma unroll
  for (int fd = 0; fd < 4; ++fd)
#pragma unroll
    for (int r = 0; r < 4; ++r) {
      float v = o[fd][r] * inv[r];
      u16 hh = f2h(v), ll = f2h(v - h2f(hh));
      int rowg = b * 2048 + n0 + w * 16 + 4 * g + r;
      int colg = h * 64 + fd * 16 + cl;
      Oh[rowg * 1024 + colg] = hh;
      Ol[rowg * 1024 + colg] = ll;
    }
}

extern "C" void kernel_launch(void* const* d_in, const int* in_sizes, int n_in,
                              void* d_out, int out_size, void* d_ws, size_t ws_size,
                              hipStream_t stream) {
  const float* x  = (const float*)d_in[0];
  const float* Wq = (const float*)d_in[1];
  const float* bq = (const float*)d_in[2];
  const float* Wp = (const float*)d_in[3];
  const float* bp = (const float*)d_in[4];
  float* out = (float*)d_out;
  char* ws = (char*)d_ws;

  u16* Xh  = (u16*)(ws + 0);         // 8MB, also Oh
  u16* Xl  = (u16*)(ws + 8388608);   // 8MB, also Ol
  u16* Wqh = (u16*)(ws + 16777216);  // 6MB
  u16* Wph = (u16*)(ws + 23068672);  // 2MB
  u16* Qh  = (u16*)(ws + 25165824);  // 8MB
  u16* Kh  = (u16*)(ws + 33554432);  // 8MB
  u16* Kl  = (u16*)(ws + 41943040);  // 8MB
  u16* Vh  = (u16*)(ws + 50331648);  // 8MB
  u16* Vl  = (u16*)(ws + 58720256);  // 8MB -> end 64MB

  k_split_all<<<8192, 256, 0, stream>>>(x, Wq, Wp, Xh, Xl, Wqh, Wph);

  k_gemm<0><<<32 * 24, 512, 0, stream>>>(Xh, Xl, Wqh, bq,
                                         Qh, Kh, Kl, Vh, Vl, nullptr, 24);
  k_attn<<<512, 512, 0, stream>>>(Qh, Kh, Kl, Vh, Vl, Xh, Xl);
  k_gemm<1><<<32 * 8, 512, 0, stream>>>(Xh, Xl, Wph, bp,
                                        nullptr, nullptr, nullptr, nullptr,
                                        nullptr, out, 8);
}